// Round 1
// baseline (582.627 us; speedup 1.0000x reference)
//
#include <hip/hip_runtime.h>
#include <math.h>

#define NN 846
#define KK 64
#define DD 256
constexpr float BN_EPS = 1e-5f;

__device__ __forceinline__ float wave_reduce_sum(float v) {
#pragma unroll
  for (int m = 32; m > 0; m >>= 1) v += __shfl_xor(v, m, 64);
  return v;
}

// async global->LDS, 16B per lane; lds dest is wave-uniform base + lane*16
__device__ __forceinline__ void stage8(const float* gsrc, float* ldst, int wv, int lane) {
#pragma unroll
  for (int r = 0; r < 2; ++r) {
    const int row = 2 * wv + r;
    __builtin_amdgcn_global_load_lds(
        (const __attribute__((address_space(1))) void*)(gsrc + row * DD + lane * 4),
        (__attribute__((address_space(3))) void*)(ldst + row * DD),
        16, 0, 0);
  }
}

extern "C" __global__ __launch_bounds__(256) void fused_gnn(
    const int* __restrict__ drug_name,
    const int* __restrict__ adj_tail,
    const int* __restrict__ adj_rel,
    const float* __restrict__ drug_table,
    const float* __restrict__ rela_table,
    const float* __restrict__ ent_table,
    const float* __restrict__ W1,
    const float* __restrict__ b1,
    const float* __restrict__ W2,
    const float* __restrict__ b2,
    const float* __restrict__ lin_w,
    const float* __restrict__ lin_b,
    float* __restrict__ x_out) {
  __shared__ float s_dr[64][68];        // DR chunk [k][dd], padded row (272B, 16B-aligned)
  __shared__ float s_w1[2][8][256];     // double-buffered W1 rows
  __shared__ float s_w2s[256];          // row-sums of W2[n]
  __shared__ float s_drug[256];
  __shared__ float s_de[512];           // concat(weighted, drug)
  __shared__ float s_b2s[64];
  __shared__ float s_score[64];
  __shared__ float s_logits[64];
  __shared__ int s_rel[64];
  __shared__ int s_tail[64];

  const int n = blockIdx.x;
  const int tid = threadIdx.x;
  const int lane = tid & 63;
  const int wv = tid >> 6;   // wave 0..3
  const int kr = tid >> 5;   // 0..7  (k-tile row)
  const int ec = tid & 31;   // 0..31 (e-tile col)
  const int e0 = ec * 8;
  const int k0 = kr * 8;

  if (tid < 64) {
    s_rel[tid] = adj_rel[n * KK + tid];
    s_tail[tid] = adj_tail[n * KK + tid];
  }
  const int dn = drug_name[n];
  s_drug[tid] = drug_table[(size_t)dn * DD + tid];

  const float* W1n = W1 + (size_t)n * DD * DD;
  const float* W2n = W2 + (size_t)n * DD * DD;

  // ---- b2 row-sums (b2 is [K][D], L2-resident) ----
#pragma unroll 4
  for (int i = 0; i < 16; ++i) {
    const int k = wv * 16 + i;
    const float4 v = *(const float4*)(b2 + (size_t)k * DD + lane * 4);
    const float p = wave_reduce_sum(v.x + v.y + v.z + v.w);
    if (lane == 0) s_b2s[k] = p;
  }

  // ---- W2[n] row-sums: wave per row, float4/lane, 8-deep ILP ----
  for (int i0 = 0; i0 < 64; i0 += 8) {
    float ps[8];
#pragma unroll
    for (int u = 0; u < 8; ++u) {
      const int r = wv * 64 + i0 + u;
      const float4 v = *(const float4*)(W2n + (size_t)r * DD + lane * 4);
      ps[u] = v.x + v.y + v.z + v.w;
    }
#pragma unroll
    for (int u = 0; u < 8; ++u) {
      const float p = wave_reduce_sum(ps[u]);
      if (lane == 0) s_w2s[wv * 64 + i0 + u] = p;
    }
  }

  // ---- GEMM: h1 = DR @ W1[n], 8x8 register tile/thread ----
  float acc[8][8];
#pragma unroll
  for (int i = 0; i < 8; ++i)
#pragma unroll
    for (int j = 0; j < 8; ++j) acc[i][j] = 0.f;

  for (int c = 0; c < 4; ++c) {   // d-chunks of 64
    const int d0 = c * 64;
    __syncthreads();  // (A) all readers of s_dr / s_w1 from prev chunk done

    // stage first 8 W1 rows of this chunk into buf0 (overlaps DR build)
    stage8(W1n + (size_t)d0 * DD, &s_w1[0][0][0], wv, lane);

    // build DR chunk: DR[k][dd] = drug[d0+dd] * rela[rel[k]][d0+dd]
    const float dv = s_drug[d0 + lane];
#pragma unroll 4
    for (int i = 0; i < 16; ++i) {
      const int k = wv * 16 + i;
      const float rl = rela_table[(size_t)s_rel[k] * DD + d0 + lane];
      s_dr[k][lane] = dv * rl;
    }
    __syncthreads();  // (B) DR ready; buf0 loads drained

    for (int s = 0; s < 8; ++s) {
      if (s) __syncthreads();  // drains stage issued last sub-chunk
      if (s < 7) stage8(W1n + (size_t)(d0 + (s + 1) * 8) * DD, &s_w1[(s + 1) & 1][0][0], wv, lane);
      const int buf = s & 1;
#pragma unroll
      for (int dd4 = 0; dd4 < 8; dd4 += 4) {
        float4 a[8];
#pragma unroll
        for (int i = 0; i < 8; ++i) a[i] = *(const float4*)&s_dr[k0 + i][s * 8 + dd4];
#pragma unroll
        for (int r = 0; r < 4; ++r) {
          const float4 w0 = *(const float4*)&s_w1[buf][dd4 + r][e0];
          const float4 w1v = *(const float4*)&s_w1[buf][dd4 + r][e0 + 4];
#pragma unroll
          for (int i = 0; i < 8; ++i) {
            const float av = (r == 0) ? a[i].x : (r == 1) ? a[i].y : (r == 2) ? a[i].z : a[i].w;
            acc[i][0] = fmaf(av, w0.x, acc[i][0]);
            acc[i][1] = fmaf(av, w0.y, acc[i][1]);
            acc[i][2] = fmaf(av, w0.z, acc[i][2]);
            acc[i][3] = fmaf(av, w0.w, acc[i][3]);
            acc[i][4] = fmaf(av, w1v.x, acc[i][4]);
            acc[i][5] = fmaf(av, w1v.y, acc[i][5]);
            acc[i][6] = fmaf(av, w1v.z, acc[i][6]);
            acc[i][7] = fmaf(av, w1v.w, acc[i][7]);
          }
        }
      }
    }
  }

  // ---- epilogue: h1 = relu(acc + b1); logit[k] = dot(h1[k,:], W2s) + b2s[k] ----
  float lg[8];
#pragma unroll
  for (int i = 0; i < 8; ++i) {
    float partial = 0.f;
#pragma unroll
    for (int jj = 0; jj < 8; jj += 4) {
      const float4 bv = *(const float4*)(b1 + (size_t)(k0 + i) * DD + e0 + jj);
      const float4 wv2 = *(const float4*)&s_w2s[e0 + jj];
      partial = fmaf(fmaxf(acc[i][jj + 0] + bv.x, 0.f), wv2.x, partial);
      partial = fmaf(fmaxf(acc[i][jj + 1] + bv.y, 0.f), wv2.y, partial);
      partial = fmaf(fmaxf(acc[i][jj + 2] + bv.z, 0.f), wv2.z, partial);
      partial = fmaf(fmaxf(acc[i][jj + 3] + bv.w, 0.f), wv2.w, partial);
    }
    // reduce across the 32 ec-lanes (stays within half-wave: masks <= 16)
#pragma unroll
    for (int m = 16; m > 0; m >>= 1) partial += __shfl_xor(partial, m, 64);
    lg[i] = partial;
  }
  if (ec == 0) {
#pragma unroll
    for (int i = 0; i < 8; ++i) s_logits[k0 + i] = lg[i] + s_b2s[k0 + i];
  }
  __syncthreads();

  // ---- softmax over K=64 (wave 0) ----
  if (wv == 0) {
    const float v = s_logits[lane];
    float mx = v;
#pragma unroll
    for (int m = 32; m > 0; m >>= 1) mx = fmaxf(mx, __shfl_xor(mx, m, 64));
    const float e = expf(v - mx);
    float ssum = e;
#pragma unroll
    for (int m = 32; m > 0; m >>= 1) ssum += __shfl_xor(ssum, m, 64);
    s_score[lane] = e / ssum;
  }
  __syncthreads();

  // ---- weighted aggregation (scores are near one-hot; skip is wave-uniform) ----
  float wsum = 0.f;
  for (int k = 0; k < KK; ++k) {
    const float sc = s_score[k];
    if (sc > 1e-12f) wsum = fmaf(sc, ent_table[(size_t)s_tail[k] * DD + tid], wsum);
  }
  s_de[tid] = wsum;
  s_de[DD + tid] = s_drug[tid];
  __syncthreads();

  // ---- x = relu([weighted, drug] @ lin_w + lin_b) ----
  float xj = lin_b[tid];
#pragma unroll 8
  for (int i = 0; i < 2 * DD; ++i) xj = fmaf(s_de[i], lin_w[(size_t)i * DD + tid], xj);
  x_out[(size_t)n * DD + tid] = fmaxf(xj, 0.f);
}

extern "C" __global__ __launch_bounds__(256) void bn_kernel(
    const float* __restrict__ x,
    const float* __restrict__ bn_w,
    const float* __restrict__ bn_b,
    float* __restrict__ out) {
  __shared__ float s_s[4], s_s2[4];
  const int d = blockIdx.x;   // one column per block
  const int tid = threadIdx.x;
  const int lane = tid & 63, wv = tid >> 6;
  float v[4];
  float s = 0.f, s2 = 0.f;
#pragma unroll
  for (int u = 0; u < 4; ++u) {
    const int r = tid + u * 256;
    v[u] = (r < NN) ? x[(size_t)r * DD + d] : 0.f;
    s += v[u];
    s2 = fmaf(v[u], v[u], s2);
  }
  s = wave_reduce_sum(s);
  s2 = wave_reduce_sum(s2);
  if (lane == 0) { s_s[wv] = s; s_s2[wv] = s2; }
  __syncthreads();
  const float S = s_s[0] + s_s[1] + s_s[2] + s_s[3];
  const float S2 = s_s2[0] + s_s2[1] + s_s2[2] + s_s2[3];
  const float mean = S / (float)NN;
  const float var = S2 / (float)NN - mean * mean;   // biased, matches jnp.var
  const float scale = (1.0f / sqrtf(var + BN_EPS)) * bn_w[d];
  const float shift = bn_b[d];
#pragma unroll
  for (int u = 0; u < 4; ++u) {
    const int r = tid + u * 256;
    if (r < NN) out[(size_t)r * DD + d] = (v[u] - mean) * scale + shift;
  }
}

extern "C" void kernel_launch(void* const* d_in, const int* in_sizes, int n_in,
                              void* d_out, int out_size, void* d_ws, size_t ws_size,
                              hipStream_t stream) {
  const int* drug_name = (const int*)d_in[0];
  const int* adj_tail = (const int*)d_in[1];
  const int* adj_rel = (const int*)d_in[2];
  const float* drug_table = (const float*)d_in[3];
  const float* rela_table = (const float*)d_in[4];
  const float* ent_table = (const float*)d_in[5];
  const float* W1 = (const float*)d_in[6];
  const float* b1 = (const float*)d_in[7];
  const float* W2 = (const float*)d_in[8];
  const float* b2 = (const float*)d_in[9];
  const float* lin_w = (const float*)d_in[10];
  const float* lin_b = (const float*)d_in[11];
  const float* bn_w = (const float*)d_in[12];
  const float* bn_b = (const float*)d_in[13];

  float* x = (float*)d_ws;  // [NN][DD] intermediate (pre-BN)

  fused_gnn<<<NN, 256, 0, stream>>>(drug_name, adj_tail, adj_rel, drug_table,
                                    rela_table, ent_table, W1, b1, W2, b2,
                                    lin_w, lin_b, x);
  bn_kernel<<<DD, 256, 0, stream>>>(x, bn_w, bn_b, (float*)d_out);
}